// Round 18
// baseline (109.937 us; speedup 1.0000x reference)
//
#include <hip/hip_runtime.h>
#include <math.h>

#define N_EMBD    4096
#define N_EXPERTS 64
#define N_TOKENS  16384
#define TAU       1e-3f
#define BM        16                  // tokens per block
#define BK        128                 // K per tile
#define NTILES    (N_EMBD / BK)       // 32

typedef __attribute__((ext_vector_type(8))) short bf16x8;
typedef __attribute__((ext_vector_type(4))) float f32x4;

#define MFMA16 __builtin_amdgcn_mfma_f32_16x16x32_bf16

struct hl_pair { unsigned h, l; };

// ---------------------------------------------------------------------------
// f32 -> (bf16 hi, bf16 lo) RNE split, pair-packed into one u32 each.
// ---------------------------------------------------------------------------
__device__ __forceinline__ hl_pair split_pair(float f0, float f1) {
    unsigned u0 = __builtin_bit_cast(unsigned, f0);
    unsigned u1 = __builtin_bit_cast(unsigned, f1);
    unsigned r0 = u0 + 0x7FFFu + ((u0 >> 16) & 1u);
    unsigned r1 = u1 + 0x7FFFu + ((u1 >> 16) & 1u);
    hl_pair p;
    p.h = (r0 >> 16) | (r1 & 0xFFFF0000u);
    float h0 = __builtin_bit_cast(float, r0 & 0xFFFF0000u);
    float h1 = __builtin_bit_cast(float, r1 & 0xFFFF0000u);
    float l0 = f0 - h0;
    float l1 = f1 - h1;
    unsigned v0 = __builtin_bit_cast(unsigned, l0);
    unsigned v1 = __builtin_bit_cast(unsigned, l1);
    unsigned s0 = v0 + 0x7FFFu + ((v0 >> 16) & 1u);
    unsigned s1 = v1 + 0x7FFFu + ((v1 >> 16) & 1u);
    p.l = (s0 >> 16) | (s1 & 0xFFFF0000u);
    return p;
}

// ---------------------------------------------------------------------------
// Kernel 0: pack W into bf16 hi/lo MFMA B-fragments; zero the flag counter.
// Frag F = ks*8 + nt*2 + term. Lane l elem j = W[nt*16+(l&15)][ks*32+(l>>4)*8+j]
// ---------------------------------------------------------------------------
__global__ void w_pack_bf16(const float* __restrict__ W,
                            uint4* __restrict__ Bpack,
                            int* __restrict__ flags) {
    int tid = blockIdx.x * blockDim.x + threadIdx.x;   // 32768
    if (tid == 0) flags[0] = 0;
    int lane = tid & 63;
    int nt   = (tid >> 6) & 3;
    int ks   = tid >> 8;                               // 0..127
    int e = nt * 16 + (lane & 15);
    int k = ks * 32 + ((lane >> 4) << 3);
    const float* src = W + (size_t)e * N_EMBD + k;
    uint4 hp, lp;
    hl_pair p0 = split_pair(src[0], src[1]);
    hl_pair p1 = split_pair(src[2], src[3]);
    hl_pair p2 = split_pair(src[4], src[5]);
    hl_pair p3 = split_pair(src[6], src[7]);
    hp.x = p0.h; lp.x = p0.l;
    hp.y = p1.h; lp.y = p1.l;
    hp.z = p2.h; lp.z = p2.l;
    hp.w = p3.h; lp.w = p3.l;
    size_t F = (size_t)ks * 8 + nt * 2;
    Bpack[F * 64 + lane]       = hp;
    Bpack[(F + 1) * 64 + lane] = lp;
}

// ---------------------------------------------------------------------------
// Split one float4 of x into bf16 hi/lo and store to swizzled LDS planes.
// hi plane at buf+[0,4096), lo plane at buf+[4096,8192).
// ---------------------------------------------------------------------------
__device__ __forceinline__ void store_split(char* buf, int off, f32x4 v) {
    hl_pair p01 = split_pair(v.x, v.y);
    hl_pair p23 = split_pair(v.z, v.w);
    uint2 hw, lw;
    hw.x = p01.h; hw.y = p23.h;
    lw.x = p01.l; lw.y = p23.l;
    *(uint2*)(buf + off)        = hw;
    *(uint2*)(buf + off + 4096) = lw;
}

// ---------------------------------------------------------------------------
// Kernel 1: fused router — r10 base (best measured, 105.7us) with the two
// remaining measured-mechanism fixes:
//  (1) B register-dbuf, issued a FULL phase ahead (r10 loaded B at use ->
//      exposed L2 latency every tile; in-order vmcnt retirement made that
//      the binding wait). Issue-order: every wait targets data >=1 phase
//      old; younger prefetches (B(t+1), A(t+2)) survive each wait.
//  (2) T5 setprio(1) around the MFMA cluster.
// Block = 16 tokens x 4 waves (wave = 16 experts); BK=128, LDS dbuf,
// raw s_barrier + lgkmcnt(0) only; swizzle = full-logical ^ ((row&7)<<4)
// both sides. Epilogue: LDS combine + top-3 + softmax + near-tie flags.
// ---------------------------------------------------------------------------
__global__ __launch_bounds__(256, 4) void router_fused(
        const float* __restrict__ x,
        const uint4* __restrict__ Bpack,
        float* __restrict__ out,
        int* __restrict__ flags) {
    __shared__ __align__(16) char ldsA[2 * 8192];   // 2 bufs x {hi,lo} planes
    __shared__ float red[BM][64];

    const int tid  = threadIdx.x;
    const int lane = tid & 63;
    const int w    = tid >> 6;                  // wave = expert quarter
    const int tok0 = blockIdx.x * BM;
    const int l15 = lane & 15, l16 = lane >> 4;

    // staging geometry: thread covers rows {row0, row0+8}, float4 col k4
    const int k4   = tid & 31;
    const int row0 = tid >> 5;                  // 0..7
    const f32x4* g0 = (const f32x4*)x + (size_t)(tok0 + row0) * (N_EMBD / 4) + k4;
    const f32x4* g1 = g0 + 8 * (N_EMBD / 4);
    const int swz = (row0 & 7) << 4;
    const int wo0 = ((row0    ) * 256 + k4 * 8) ^ swz;
    const int wo1 = ((row0 + 8) * 256 + k4 * 8) ^ swz;

    // fragment read offsets: full-logical XOR (r9 fix)
    const int swz_r = (l15 & 7) << 4;
    const int ro_base = l15 * 256 + l16 * 16;
    const int off0 = (ro_base +   0) ^ swz_r;
    const int off1 = (ro_base +  64) ^ swz_r;
    const int off2 = (ro_base + 128) ^ swz_r;
    const int off3 = (ro_base + 192) ^ swz_r;

    f32x4 acc = {0.f, 0.f, 0.f, 0.f};
    f32x4 r0, r1;                                // A prefetch (1 phase)
    uint4 bA0h, bA0l, bA1h, bA1l, bA2h, bA2l, bA3h, bA3l;   // B dbuf A
    uint4 bB0h, bB0l, bB1h, bB1l, bB2h, bB2l, bB3h, bB3l;   // B dbuf B

    char* buf0 = ldsA;
    char* buf1 = ldsA + 8192;

#define LOADA(t) { r0 = g0[(t) * 32]; r1 = g1[(t) * 32]; }
#define STOREA(buf) { store_split(buf, wo0, r0); store_split(buf, wo1, r1); }
#define LOADB(P, tt) { const uint4* bq = Bpack                                \
        + ((size_t)((tt) * 4) * 8 + w * 2) * 64 + lane;                       \
    P##0h = bq[0];    P##0l = bq[64];                                         \
    P##1h = bq[512];  P##1l = bq[576];                                        \
    P##2h = bq[1024]; P##2l = bq[1088];                                       \
    P##3h = bq[1536]; P##3l = bq[1600]; }
#define COMPUTE(bufR, P) {                                                    \
    bf16x8 ah, al, bh, bl;                                                    \
    __builtin_amdgcn_s_setprio(1);                                            \
    bh = __builtin_bit_cast(bf16x8, P##0h); bl = __builtin_bit_cast(bf16x8, P##0l); \
    ah = *(const bf16x8*)((bufR) + off0);                                     \
    al = *(const bf16x8*)((bufR) + off0 + 4096);                              \
    acc = MFMA16(ah, bh, acc, 0, 0, 0);                                       \
    acc = MFMA16(ah, bl, acc, 0, 0, 0);                                       \
    acc = MFMA16(al, bh, acc, 0, 0, 0);                                       \
    bh = __builtin_bit_cast(bf16x8, P##1h); bl = __builtin_bit_cast(bf16x8, P##1l); \
    ah = *(const bf16x8*)((bufR) + off1);                                     \
    al = *(const bf16x8*)((bufR) + off1 + 4096);                              \
    acc = MFMA16(ah, bh, acc, 0, 0, 0);                                       \
    acc = MFMA16(ah, bl, acc, 0, 0, 0);                                       \
    acc = MFMA16(al, bh, acc, 0, 0, 0);                                       \
    bh = __builtin_bit_cast(bf16x8, P##2h); bl = __builtin_bit_cast(bf16x8, P##2l); \
    ah = *(const bf16x8*)((bufR) + off2);                                     \
    al = *(const bf16x8*)((bufR) + off2 + 4096);                              \
    acc = MFMA16(ah, bh, acc, 0, 0, 0);                                       \
    acc = MFMA16(ah, bl, acc, 0, 0, 0);                                       \
    acc = MFMA16(al, bh, acc, 0, 0, 0);                                       \
    bh = __builtin_bit_cast(bf16x8, P##3h); bl = __builtin_bit_cast(bf16x8, P##3l); \
    ah = *(const bf16x8*)((bufR) + off3);                                     \
    al = *(const bf16x8*)((bufR) + off3 + 4096);                              \
    acc = MFMA16(ah, bh, acc, 0, 0, 0);                                       \
    acc = MFMA16(ah, bl, acc, 0, 0, 0);                                       \
    acc = MFMA16(al, bh, acc, 0, 0, 0);                                       \
    __builtin_amdgcn_s_setprio(0); }

    // prologue: stage tile 0; issue B(0) and A(1) (both used next phase)
    LOADA(0);
    STOREA(buf0);                              // one-time stall for A(0)
    LOADB(bA, 0);
    LOADA(1);
    __builtin_amdgcn_sched_barrier(0);
    asm volatile("s_waitcnt lgkmcnt(0)" ::: "memory");
    __builtin_amdgcn_s_barrier();
    __builtin_amdgcn_sched_barrier(0);

    for (int t = 0; t < NTILES; t += 2) {
        // ---- even phase: tile t on buf0 with B=bA ----
        LOADB(bB, t + 1);                      // B(t+1): youngest, survives waits
        __builtin_amdgcn_sched_barrier(0);
        COMPUTE(buf0, bA);                     // waits bA (issued 1 phase ago)
        STOREA(buf1);                          // waits r = A(t+1) (1 phase old)
        if (t + 2 < NTILES) LOADA(t + 2);
        __builtin_amdgcn_sched_barrier(0);
        asm volatile("s_waitcnt lgkmcnt(0)" ::: "memory");
        __builtin_amdgcn_s_barrier();
        __builtin_amdgcn_sched_barrier(0);

        // ---- odd phase: tile t+1 on buf1 with B=bB ----
        if (t + 2 < NTILES) {
            LOADB(bA, t + 2);
            __builtin_amdgcn_sched_barrier(0);
            COMPUTE(buf1, bB);
            STOREA(buf0);                      // waits r = A(t+2)
            if (t + 3 < NTILES) LOADA(t + 3);
            __builtin_amdgcn_sched_barrier(0);
            asm volatile("s_waitcnt lgkmcnt(0)" ::: "memory");
            __builtin_amdgcn_s_barrier();
            __builtin_amdgcn_sched_barrier(0);
        } else {
            COMPUTE(buf1, bB);                 // final tile
        }
    }
#undef LOADA
#undef STOREA
#undef LOADB
#undef COMPUTE

    // C layout: row(token) = (lane>>4)*4 + reg, col(expert in quarter) = lane&15
    const int rb = l16 << 2;
#pragma unroll
    for (int j = 0; j < 4; ++j)
        red[rb + j][w * 16 + l15] = acc[j];
    __syncthreads();

    // wave w finalizes tokens w*4 .. w*4+3; lane = expert
    for (int tt = 0; tt < 4; ++tt) {
        const int t = w * 4 + tt;
        float v = red[t][lane];

        float m1 = v; int i1 = lane;
#pragma unroll
        for (int off = 32; off; off >>= 1) {
            float ov = __shfl_xor(m1, off); int oi = __shfl_xor(i1, off);
            if (ov > m1 || (ov == m1 && oi < i1)) { m1 = ov; i1 = oi; }
        }
        float m2 = (lane == i1) ? -INFINITY : v; int i2 = lane;
#pragma unroll
        for (int off = 32; off; off >>= 1) {
            float ov = __shfl_xor(m2, off); int oi = __shfl_xor(i2, off);
            if (ov > m2 || (ov == m2 && oi < i2)) { m2 = ov; i2 = oi; }
        }
        float m3 = (lane == i1 || lane == i2) ? -INFINITY : v;
#pragma unroll
        for (int off = 32; off; off >>= 1)
            m3 = fmaxf(m3, __shfl_xor(m3, off));

        if (lane == 0) {
            const int tok = tok0 + t;
            float e2  = __expf(m2 - m1);
            float inv = 1.0f / (1.0f + e2);
            float2 idx = make_float2((float)i1, (float)i2);
            float2 gts = make_float2(inv, e2 * inv);
            *(float2*)(out + 2 * tok) = idx;
            *(float2*)(out + 2 * N_TOKENS + 2 * tok) = gts;
            if ((m1 - m2 < TAU) || (m2 - m3 < TAU)) {
                int p = atomicAdd(flags, 1);
                if (p < N_TOKENS) flags[1 + p] = tok;
            }
        }
    }
}

// ---------------------------------------------------------------------------
// Kernel 2: exact f64 refinement of flagged near-tie tokens. Block per token
// (grid-strided). Wave wv handles experts wv*16..+16, lanes split K.
// ---------------------------------------------------------------------------
__global__ __launch_bounds__(256) void refine(const float* __restrict__ x,
                                              const float* __restrict__ W,
                                              const int* __restrict__ flags,
                                              float* __restrict__ out) {
    __shared__ double redd[64];
    const int lane = threadIdx.x & 63;
    const int wv   = threadIdx.x >> 6;
    int cnt = flags[0];
    if (cnt > N_TOKENS) cnt = N_TOKENS;

    for (int i = blockIdx.x; i < cnt; i += gridDim.x) {
        const int tok = flags[1 + i];
        const float4* xr4 = (const float4*)(x + (size_t)tok * N_EMBD);
#pragma unroll
        for (int ee = 0; ee < 16; ++ee) {
            const int e = wv * 16 + ee;
            const float4* wr = (const float4*)(W + (size_t)e * N_EMBD);
            double acc = 0.0;
#pragma unroll 4
            for (int c = 0; c < 16; ++c) {
                float4 xv = xr4[c * 64 + lane];
                float4 wq = wr[c * 64 + lane];
                acc += (double)xv.x * wq.x + (double)xv.y * wq.y
                     + (double)xv.z * wq.z + (double)xv.w * wq.w;
            }
#pragma unroll
            for (int off = 32; off; off >>= 1)
                acc += __shfl_xor(acc, off);
            if (lane == 0) redd[e] = acc;
        }
        __syncthreads();
        if (wv == 0) {
            double v = redd[lane];
            double m1 = v; int i1 = lane;
#pragma unroll
            for (int off = 32; off; off >>= 1) {
                double ov = __shfl_xor(m1, off); int oi = __shfl_xor(i1, off);
                if (ov > m1 || (ov == m1 && oi < i1)) { m1 = ov; i1 = oi; }
            }
            double m2 = (lane == i1) ? -INFINITY : v; int i2 = lane;
#pragma unroll
            for (int off = 32; off; off >>= 1) {
                double ov = __shfl_xor(m2, off); int oi = __shfl_xor(i2, off);
                if (ov > m2 || (ov == m2 && oi < i2)) { m2 = ov; i2 = oi; }
            }
            if (lane == 0) {
                double e2  = exp(m2 - m1);
                double inv = 1.0 / (1.0 + e2);
                out[2 * tok + 0] = (float)i1;
                out[2 * tok + 1] = (float)i2;
                out[2 * N_TOKENS + 2 * tok + 0] = (float)inv;
                out[2 * N_TOKENS + 2 * tok + 1] = (float)(e2 * inv);
            }
        }
        __syncthreads();
    }
}

// ---------------------------------------------------------------------------
extern "C" void kernel_launch(void* const* d_in, const int* in_sizes, int n_in,
                              void* d_out, int out_size, void* d_ws, size_t ws_size,
                              hipStream_t stream) {
    const float* x = (const float*)d_in[0];
    const float* W = (const float*)d_in[1];
    float* out = (float*)d_out;

    uint4* Bpack = (uint4*)d_ws;                          // [0, 1MB)
    int*   flags = (int*)((char*)d_ws + (2u << 20));      // [2MB, ...)

    w_pack_bf16 <<<128, 256, 0, stream>>>(W, Bpack, flags);
    router_fused<<<N_TOKENS / BM, 256, 0, stream>>>(x, Bpack, out, flags);
    refine      <<<128, 256, 0, stream>>>(x, W, flags, out);
}